// Round 15
// baseline (759.459 us; speedup 1.0000x reference)
//
#include <hip/hip_runtime.h>
#include <hip/hip_bf16.h>

#define NEG_SLOPE 0.01f
#define NPB 512          // nodes per coarse bucket (dst >> 9)
#define QN  128          // nodes per fused block (quarter bucket)
#define CHUNK 2048       // edges per block in partition pass
#define GROWS 128        // rows per GEMM block
#define ELCAP 4096       // per-quarter compacted edge list capacity

typedef __attribute__((ext_vector_type(8))) short short8;
typedef __attribute__((ext_vector_type(4))) float f32x4;

__device__ __forceinline__ unsigned short f2bf_rne(float f) {
    unsigned u = __float_as_uint(f);
    u += 0x7FFFu + ((u >> 16) & 1u);       // round-to-nearest-even
    return (unsigned short)(u >> 16);
}

// 64-wide inclusive wave scan (no barriers).
__device__ __forceinline__ unsigned wscan_incl(unsigned v) {
    const int ln = threadIdx.x & 63;
#pragma unroll
    for (int off = 1; off < 64; off <<= 1) {
        unsigned x = __shfl_up(v, off);
        if (ln >= off) v += x;
    }
    return v;
}

// Fused K1: parity-interleaved roles — even pair-idx = MFMA GEMM
// (z = h @ W1^T bf16, + s,t), odd = edge partition. (unchanged from r14)
__global__ __launch_bounds__(256, 2) void k_gp(
    const float* __restrict__ h, const float* __restrict__ W1,
    const float* __restrict__ Wa, unsigned short* __restrict__ zb,
    float* __restrict__ s, float* __restrict__ t, int N, int G1,
    const int* __restrict__ src, const int* __restrict__ dst,
    unsigned* __restrict__ gcur, unsigned* __restrict__ table,
    int E, int NBKT, int BCAP, int minG)
{
    __shared__ __align__(16) union SM {
        struct { short wsb[64 * 128]; short tbuf[4][16 * 64]; } g;       // 24 KB
        struct {
            unsigned cnt[256]; unsigned exc[256]; unsigned gbaseb[256];
            unsigned wtot[4];
            unsigned stage[CHUNK]; unsigned short bkt[CHUNK];
        } p;
    } sm;
    const int tid = threadIdx.x;
    const int bid = blockIdx.x;

    int role, idx;
    if (bid < 2 * minG) { role = bid & 1; idx = bid >> 1; }
    else { role = (G1 > minG) ? 0 : 1; idx = minG + (bid - 2 * minG); }

    if (role == 0) {
        // ---------------- GEMM path ----------------
        const int nb = idx * GROWS;
        const int w  = tid >> 6;
        const int l  = tid & 63;
        const int lr = l & 15;
        const int lc = l >> 4;
        const int rowbase = nb + w * 32;
        const float4* __restrict__ h4 = (const float4*)h;
        const float4* __restrict__ W14 = (const float4*)W1;

        float asrc[4], adst[4];
#pragma unroll
        for (int ni = 0; ni < 4; ++ni) {
            asrc[ni] = Wa[ni * 16 + lr];
            adst[ni] = Wa[64 + ni * 16 + lr];
        }

        float4 av[8];
        {
            const int myn = rowbase + lr;
#pragma unroll
            for (int ks = 0; ks < 4; ++ks) {
                const int kcb = ks * 4 + lc;
                if (myn < N) {
                    av[2 * ks]     = h4[(size_t)myn * 32 + kcb * 2];
                    av[2 * ks + 1] = h4[(size_t)myn * 32 + kcb * 2 + 1];
                } else {
                    av[2 * ks]     = make_float4(0.f, 0.f, 0.f, 0.f);
                    av[2 * ks + 1] = make_float4(0.f, 0.f, 0.f, 0.f);
                }
            }
        }

#pragma unroll
        for (int it = 0; it < 4; ++it) {
            const int q = tid + it * 256;
            const int r = q >> 4, cb = q & 15;
            float4 v0 = W14[(size_t)r * 32 + cb * 2];
            float4 v1 = W14[(size_t)r * 32 + cb * 2 + 1];
            short8 o;
            o[0]=f2bf_rne(v0.x); o[1]=f2bf_rne(v0.y); o[2]=f2bf_rne(v0.z); o[3]=f2bf_rne(v0.w);
            o[4]=f2bf_rne(v1.x); o[5]=f2bf_rne(v1.y); o[6]=f2bf_rne(v1.z); o[7]=f2bf_rne(v1.w);
            *(short8*)&sm.g.wsb[r * 128 + ((cb * 8) ^ ((r & 7) << 3))] = o;
        }
        __syncthreads();

        short* __restrict__ tb = sm.g.tbuf[w];

#pragma unroll
        for (int rg = 0; rg < 2; ++rg) {
            short8 afr[4];
#pragma unroll
            for (int ks = 0; ks < 4; ++ks) {
                const float4 v0 = av[2 * ks], v1 = av[2 * ks + 1];
                short8 o;
                o[0]=f2bf_rne(v0.x); o[1]=f2bf_rne(v0.y); o[2]=f2bf_rne(v0.z); o[3]=f2bf_rne(v0.w);
                o[4]=f2bf_rne(v1.x); o[5]=f2bf_rne(v1.y); o[6]=f2bf_rne(v1.z); o[7]=f2bf_rne(v1.w);
                afr[ks] = o;
            }
            if (rg < 1) {
                const int myn = rowbase + 16 + lr;
#pragma unroll
                for (int ks = 0; ks < 4; ++ks) {
                    const int kcb = ks * 4 + lc;
                    if (myn < N) {
                        av[2 * ks]     = h4[(size_t)myn * 32 + kcb * 2];
                        av[2 * ks + 1] = h4[(size_t)myn * 32 + kcb * 2 + 1];
                    } else {
                        av[2 * ks]     = make_float4(0.f, 0.f, 0.f, 0.f);
                        av[2 * ks + 1] = make_float4(0.f, 0.f, 0.f, 0.f);
                    }
                }
            }

            f32x4 acc[4];
#pragma unroll
            for (int ni = 0; ni < 4; ++ni) acc[ni] = (f32x4){0.f, 0.f, 0.f, 0.f};
#pragma unroll
            for (int ks = 0; ks < 4; ++ks) {
                const int kcb = ks * 4 + lc;
#pragma unroll
                for (int ni = 0; ni < 4; ++ni) {
                    const int wr = ni * 16 + lr;
                    const short8 bf = *(const short8*)&sm.g.wsb[wr * 128 + ((kcb * 8) ^ ((wr & 7) << 3))];
                    acc[ni] = __builtin_amdgcn_mfma_f32_16x16x32_bf16(afr[ks], bf, acc[ni], 0, 0, 0);
                }
            }

#pragma unroll
            for (int r = 0; r < 4; ++r) {
                float ps = 0.f, pt = 0.f;
#pragma unroll
                for (int ni = 0; ni < 4; ++ni) {
                    ps = fmaf(acc[ni][r], asrc[ni], ps);
                    pt = fmaf(acc[ni][r], adst[ni], pt);
                }
#pragma unroll
                for (int m = 1; m < 16; m <<= 1) {
                    ps += __shfl_xor(ps, m);
                    pt += __shfl_xor(pt, m);
                }
                const int node = rowbase + rg * 16 + lc * 4 + r;
                if (lr == 0 && node < N) { s[node] = ps; t[node] = pt; }
            }

#pragma unroll
            for (int ni = 0; ni < 4; ++ni) {
                const int col = ni * 16 + lr;
#pragma unroll
                for (int r = 0; r < 4; ++r) {
                    const int ro = lc * 4 + r;
                    tb[ro * 64 + (((col >> 3) ^ (ro & 7)) << 3) + (col & 7)]
                        = (short)f2bf_rne(acc[ni][r]);
                }
            }
            {
                const int ro = l >> 2;
                const int n = rowbase + rg * 16 + ro;
                if (n < N) {
#pragma unroll
                    for (int j = 0; j < 2; ++j) {
                        const int c = (l & 3) * 2 + j;
                        const short8 v = *(const short8*)&tb[ro * 64 + ((c ^ (ro & 7)) << 3)];
                        *(short8*)&zb[(size_t)n * 64 + c * 8] = v;
                    }
                }
            }
        }
    } else {
        // ---------------- Partition path ----------------
        const int e0 = idx * CHUNK;
        const int nE = min(CHUNK, E - e0);

        sm.p.cnt[tid] = 0u;
        __syncthreads();
        for (int i = tid; i < nE; i += 256)
            atomicAdd(&sm.p.cnt[(unsigned)dst[e0 + i] >> 9], 1u);
        __syncthreads();

        const unsigned myc = sm.p.cnt[tid];
        if (tid < NBKT && myc > 0u) sm.p.gbaseb[tid] = atomicAdd(&gcur[tid], myc);

        const unsigned inc = wscan_incl(myc);
        if ((tid & 63) == 63) sm.p.wtot[tid >> 6] = inc;
        sm.p.cnt[tid] = 0u;
        __syncthreads();
        {
            unsigned wo = 0;
            const int mw = tid >> 6;
#pragma unroll
            for (int ww = 0; ww < 4; ++ww)
                if (ww < mw) wo += sm.p.wtot[ww];
            sm.p.exc[tid] = wo + inc - myc;
        }
        __syncthreads();

        for (int i = tid; i < nE; i += 256) {
            const unsigned d = (unsigned)dst[e0 + i];
            const unsigned b = d >> 9;
            const unsigned pos = sm.p.exc[b] + atomicAdd(&sm.p.cnt[b], 1u);
            sm.p.stage[pos] = ((unsigned)src[e0 + i] << 9) | (d & 511u);
            sm.p.bkt[pos] = (unsigned short)b;
        }
        __syncthreads();

        for (int i = tid; i < nE; i += 256) {
            const unsigned b = sm.p.bkt[i];
            const unsigned off = sm.p.gbaseb[b] + ((unsigned)i - sm.p.exc[b]);
            if (off < (unsigned)BCAP)
                table[(size_t)b * BCAP + off] = sm.p.stage[i];
        }
    }
}

// Fused softmax + aggregate, all-in-LDS. One block per QUARTER bucket
// (128 nodes). Phase A: ballot-compact this quarter's edges from the bucket's
// table segment. Phase B: per edge, p = exp(leaky(s+t)), fire-and-forget LDS
// f32 atomics into acc[128][65] (pad 65 -> bank spread by node) + den.
// Epilogue: coalesced float4 stores of acc/den.
__global__ __launch_bounds__(256) void k_fuse(
    const unsigned* __restrict__ table, const unsigned* __restrict__ gcur,
    const float* __restrict__ s, const float* __restrict__ t,
    const unsigned short* __restrict__ zb, float* __restrict__ out,
    int N, int BCAP)
{
    __shared__ float acc[QN * 65];       // 33.3 KB
    __shared__ float den[QN];
    __shared__ float tl[QN];
    __shared__ unsigned elist[ELCAP];    // 16 KB
    __shared__ unsigned ecnt;

    const int tid = threadIdx.x;
    const int b   = blockIdx.x >> 2;     // coarse bucket
    const int qr  = blockIdx.x & 3;      // quarter
    const int node0 = b * NPB + qr * QN;
    const int bc = min((int)gcur[b], BCAP);
    const size_t tbo = (size_t)b * BCAP;

    // init
    for (int i = tid; i < QN * 65; i += 256) acc[i] = 0.f;
    if (tid < QN) {
        const int n = node0 + tid;
        den[tid] = 0.f;
        tl[tid] = (n < N) ? t[n] : 0.f;
    }
    if (tid == 0) ecnt = 0u;
    __syncthreads();

    // Phase A: compact this quarter's edges (1 LDS atomic per wave-iter).
    const int lane = tid & 63;
    const unsigned long long below = (1ull << lane) - 1ull;
    for (int i = tid; i < ((bc + 255) & ~255); i += 256) {
        unsigned v = 0u;
        bool rel = false;
        if (i < bc) {
            v = table[tbo + i];
            rel = ((int)((v & 511u) >> 7) == qr);
        }
        const unsigned long long m = __ballot(rel);
        unsigned b0 = 0u;
        if (lane == 0) b0 = atomicAdd(&ecnt, (unsigned)__popcll(m));
        b0 = __shfl(b0, 0);
        if (rel) {
            const unsigned pos = b0 + (unsigned)__popcll(m & below);
            if (pos < ELCAP)
                elist[pos] = ((v >> 9) << 7) | (v & 127u);
        }
    }
    __syncthreads();
    const int en = min((int)ecnt, ELCAP);

    // Phase B: per-edge accumulate (thread = edge).
    for (int i = tid; i < en; i += 256) {
        const unsigned v = elist[i];
        const unsigned l = v & 127u;
        const int sj = (int)(v >> 7);
        float e = s[sj] + tl[l];
        e = (e >= 0.f) ? e : NEG_SLOPE * e;
        const float p = __expf(e);
        atomicAdd(&den[l], p);
        float* __restrict__ arow = &acc[l * 65];
        const uint4* __restrict__ zr = (const uint4*)&zb[(size_t)sj * 64];
        uint4 zz[8];
#pragma unroll
        for (int c = 0; c < 8; ++c) zz[c] = zr[c];
#pragma unroll
        for (int c = 0; c < 8; ++c) {
            const uint4 zv = zz[c];
            atomicAdd(&arow[8 * c + 0], p * __uint_as_float(zv.x << 16));
            atomicAdd(&arow[8 * c + 1], p * __uint_as_float(zv.x & 0xFFFF0000u));
            atomicAdd(&arow[8 * c + 2], p * __uint_as_float(zv.y << 16));
            atomicAdd(&arow[8 * c + 3], p * __uint_as_float(zv.y & 0xFFFF0000u));
            atomicAdd(&arow[8 * c + 4], p * __uint_as_float(zv.z << 16));
            atomicAdd(&arow[8 * c + 5], p * __uint_as_float(zv.z & 0xFFFF0000u));
            atomicAdd(&arow[8 * c + 6], p * __uint_as_float(zv.w << 16));
            atomicAdd(&arow[8 * c + 7], p * __uint_as_float(zv.w & 0xFFFF0000u));
        }
    }
    __syncthreads();

    // Epilogue: out[node] = acc / den, coalesced float4 stores.
    for (int q = tid; q < QN * 16; q += 256) {
        const int n  = q >> 4;          // local node
        const int c4 = q & 15;          // float4 index
        const int gn = node0 + n;
        if (gn >= N) continue;
        const float inv = 1.f / fmaxf(den[n], 1e-16f);
        const float* a = &acc[n * 65 + c4 * 4];
        float4 o = make_float4(a[0] * inv, a[1] * inv, a[2] * inv, a[3] * inv);
        *(float4*)&out[(size_t)gn * 64 + c4 * 4] = o;
    }
}

extern "C" void kernel_launch(void* const* d_in, const int* in_sizes, int n_in,
                              void* d_out, int out_size, void* d_ws, size_t ws_size,
                              hipStream_t stream) {
    const float* h   = (const float*)d_in[0];
    const int*   src = (const int*)d_in[1];
    const int*   dst = (const int*)d_in[2];
    const float* W1  = (const float*)d_in[3];
    const float* Wa  = (const float*)d_in[4];
    float* out = (float*)d_out;

    const int N = in_sizes[0] / 128;
    const int E = in_sizes[1];
    const int NBKT = (N + NPB - 1) / NPB;            // <=256
    const int meanb = (E + NBKT - 1) / NBKT;
    int slack = 24 * (int)sqrtf((float)meanb) + 64;  // mean + 24 sigma
    const int BCAP = meanb + slack;

    const int G1 = (N + GROWS - 1) / GROWS;          // gemm blocks
    const int G2 = (E + CHUNK - 1) / CHUNK;          // partition blocks
    const int minG = (G1 < G2) ? G1 : G2;

    // ws: zb(N*64 bf16) | s(N) | t(N) | gcur(NBKT) | table(NBKT*BCAP)
    unsigned short* zb = (unsigned short*)d_ws;
    float*    s        = (float*)(zb + (size_t)N * 64);
    float*    t        = s + N;
    unsigned* gcur     = (unsigned*)(t + N);
    unsigned* table    = gcur + NBKT;

    hipMemsetAsync(gcur, 0, (size_t)NBKT * sizeof(unsigned), stream);

    k_gp<<<G1 + G2, 256, 0, stream>>>(h, W1, Wa, zb, s, t, N, G1,
                                      src, dst, gcur, table, E, NBKT, BCAP, minG);
    k_fuse<<<NBKT * 4, 256, 0, stream>>>(table, gcur, s, t, zb, out, N, BCAP);
}

// Round 16
// 95.142 us; speedup vs baseline: 7.9824x; 7.9824x over previous
//
#include <hip/hip_runtime.h>
#include <hip/hip_bf16.h>

#define NEG_SLOPE 0.01f
#define NPB 512          // nodes per coarse bucket (dst >> 9)
#define CHUNK 4096       // edges per block in partition pass

typedef __attribute__((ext_vector_type(8))) short short8;
typedef __attribute__((ext_vector_type(4))) float f32x4;

__device__ __forceinline__ unsigned short f2bf_rne(float f) {
    unsigned u = __float_as_uint(f);
    u += 0x7FFFu + ((u >> 16) & 1u);       // round-to-nearest-even
    return (unsigned short)(u >> 16);
}

// Fused K1: blocks [0, G1) = MFMA GEMM (z = h @ W1^T bf16, + s,t from f32 acc);
// blocks [G1, G1+G2) = edge partition pass. Disjoint data -> safe overlap.
__global__ __launch_bounds__(256, 4) void k_gp(
    const float* __restrict__ h, const float* __restrict__ W1,
    const float* __restrict__ Wa, unsigned short* __restrict__ zb,
    float* __restrict__ s, float* __restrict__ t, int N, int G1,
    const int* __restrict__ src, const int* __restrict__ dst,
    unsigned* __restrict__ gcur, unsigned* __restrict__ table,
    int E, int NBKT, int BCAP)
{
    __shared__ __align__(16) union SM {
        struct { short wsb[64 * 128]; short tbuf[4][16 * 64]; } g;       // 24 KB
        struct {
            unsigned cnt[256]; unsigned exc[256]; unsigned sbuf[256];
            unsigned gbaseb[256]; unsigned stage[CHUNK];
            unsigned short bkt[CHUNK];
        } p;                                                             // 28 KB
    } sm;
    const int tid = threadIdx.x;

    if (blockIdx.x < (unsigned)G1) {
        // ---------------- GEMM path ----------------
        const int nb = blockIdx.x * 256;
        const int w  = tid >> 6;
        const int l  = tid & 63;
        const int lr = l & 15;
        const int lc = l >> 4;
        const int rowbase = nb + w * 64;
        const float4* __restrict__ h4 = (const float4*)h;
        const float4* __restrict__ W14 = (const float4*)W1;

        float asrc[4], adst[4];
#pragma unroll
        for (int ni = 0; ni < 4; ++ni) {
            asrc[ni] = Wa[ni * 16 + lr];
            adst[ni] = Wa[64 + ni * 16 + lr];
        }

        float4 av[8];
        {
            const int myn = rowbase + lr;
#pragma unroll
            for (int ks = 0; ks < 4; ++ks) {
                const int kcb = ks * 4 + lc;
                if (myn < N) {
                    av[2 * ks]     = h4[(size_t)myn * 32 + kcb * 2];
                    av[2 * ks + 1] = h4[(size_t)myn * 32 + kcb * 2 + 1];
                } else {
                    av[2 * ks]     = make_float4(0.f, 0.f, 0.f, 0.f);
                    av[2 * ks + 1] = make_float4(0.f, 0.f, 0.f, 0.f);
                }
            }
        }

#pragma unroll
        for (int it = 0; it < 4; ++it) {
            const int q = tid + it * 256;
            const int r = q >> 4, cb = q & 15;
            float4 v0 = W14[(size_t)r * 32 + cb * 2];
            float4 v1 = W14[(size_t)r * 32 + cb * 2 + 1];
            short8 o;
            o[0]=f2bf_rne(v0.x); o[1]=f2bf_rne(v0.y); o[2]=f2bf_rne(v0.z); o[3]=f2bf_rne(v0.w);
            o[4]=f2bf_rne(v1.x); o[5]=f2bf_rne(v1.y); o[6]=f2bf_rne(v1.z); o[7]=f2bf_rne(v1.w);
            *(short8*)&sm.g.wsb[r * 128 + ((cb * 8) ^ ((r & 7) << 3))] = o;
        }
        __syncthreads();

        short* __restrict__ tb = sm.g.tbuf[w];      // per-wave, no barriers

#pragma unroll
        for (int rg = 0; rg < 4; ++rg) {
            short8 afr[4];
#pragma unroll
            for (int ks = 0; ks < 4; ++ks) {
                const float4 v0 = av[2 * ks], v1 = av[2 * ks + 1];
                short8 o;
                o[0]=f2bf_rne(v0.x); o[1]=f2bf_rne(v0.y); o[2]=f2bf_rne(v0.z); o[3]=f2bf_rne(v0.w);
                o[4]=f2bf_rne(v1.x); o[5]=f2bf_rne(v1.y); o[6]=f2bf_rne(v1.z); o[7]=f2bf_rne(v1.w);
                afr[ks] = o;
            }
            if (rg < 3) {
                const int myn = rowbase + (rg + 1) * 16 + lr;
#pragma unroll
                for (int ks = 0; ks < 4; ++ks) {
                    const int kcb = ks * 4 + lc;
                    if (myn < N) {
                        av[2 * ks]     = h4[(size_t)myn * 32 + kcb * 2];
                        av[2 * ks + 1] = h4[(size_t)myn * 32 + kcb * 2 + 1];
                    } else {
                        av[2 * ks]     = make_float4(0.f, 0.f, 0.f, 0.f);
                        av[2 * ks + 1] = make_float4(0.f, 0.f, 0.f, 0.f);
                    }
                }
            }

            f32x4 acc[4];
#pragma unroll
            for (int ni = 0; ni < 4; ++ni) acc[ni] = (f32x4){0.f, 0.f, 0.f, 0.f};
#pragma unroll
            for (int ks = 0; ks < 4; ++ks) {
                const int kcb = ks * 4 + lc;
#pragma unroll
                for (int ni = 0; ni < 4; ++ni) {
                    const int wr = ni * 16 + lr;
                    const short8 bf = *(const short8*)&sm.g.wsb[wr * 128 + ((kcb * 8) ^ ((wr & 7) << 3))];
                    acc[ni] = __builtin_amdgcn_mfma_f32_16x16x32_bf16(afr[ks], bf, acc[ni], 0, 0, 0);
                }
            }

            // s,t epilogue (f32 acc). C/D: col = lr, row = lc*4 + r.
#pragma unroll
            for (int r = 0; r < 4; ++r) {
                float ps = 0.f, pt = 0.f;
#pragma unroll
                for (int ni = 0; ni < 4; ++ni) {
                    ps = fmaf(acc[ni][r], asrc[ni], ps);
                    pt = fmaf(acc[ni][r], adst[ni], pt);
                }
#pragma unroll
                for (int m = 1; m < 16; m <<= 1) {
                    ps += __shfl_xor(ps, m);
                    pt += __shfl_xor(pt, m);
                }
                const int node = rowbase + rg * 16 + lc * 4 + r;
                if (lr == 0 && node < N) { s[node] = ps; t[node] = pt; }
            }

            // z transpose via per-wave LDS -> coalesced 16B stores.
#pragma unroll
            for (int ni = 0; ni < 4; ++ni) {
                const int col = ni * 16 + lr;
#pragma unroll
                for (int r = 0; r < 4; ++r) {
                    const int ro = lc * 4 + r;
                    tb[ro * 64 + (((col >> 3) ^ (ro & 7)) << 3) + (col & 7)]
                        = (short)f2bf_rne(acc[ni][r]);
                }
            }
            {
                const int ro = l >> 2;
                const int n = rowbase + rg * 16 + ro;
                if (n < N) {
#pragma unroll
                    for (int j = 0; j < 2; ++j) {
                        const int c = (l & 3) * 2 + j;
                        const short8 v = *(const short8*)&tb[ro * 64 + ((c ^ (ro & 7)) << 3)];
                        *(short8*)&zb[(size_t)n * 64 + c * 8] = v;
                    }
                }
            }
        }
    } else {
        // ---------------- Partition path ----------------
        const int e0 = (blockIdx.x - G1) * CHUNK;
        const int nE = min(CHUNK, E - e0);

        sm.p.cnt[tid] = 0u;
        __syncthreads();
        for (int i = tid; i < nE; i += 256)
            atomicAdd(&sm.p.cnt[(unsigned)dst[e0 + i] >> 9], 1u);
        __syncthreads();

        const unsigned myc = sm.p.cnt[tid];
        if (tid < NBKT && myc > 0u) sm.p.gbaseb[tid] = atomicAdd(&gcur[tid], myc);

        sm.p.sbuf[tid] = myc;
        __syncthreads();
        for (int off = 1; off < 256; off <<= 1) {
            unsigned x = (tid >= off) ? sm.p.sbuf[tid - off] : 0u;
            __syncthreads();
            sm.p.sbuf[tid] += x;
            __syncthreads();
        }
        sm.p.exc[tid] = sm.p.sbuf[tid] - myc;
        __syncthreads();
        sm.p.cnt[tid] = 0u;
        __syncthreads();

        for (int i = tid; i < nE; i += 256) {
            const unsigned d = (unsigned)dst[e0 + i];
            const unsigned b = d >> 9;
            const unsigned pos = sm.p.exc[b] + atomicAdd(&sm.p.cnt[b], 1u);
            sm.p.stage[pos] = ((unsigned)src[e0 + i] << 9) | (d & 511u);
            sm.p.bkt[pos] = (unsigned short)b;
        }
        __syncthreads();

        for (int i = tid; i < nE; i += 256) {
            const unsigned b = sm.p.bkt[i];
            const unsigned off = sm.p.gbaseb[b] + ((unsigned)i - sm.p.exc[b]);
            if (off < (unsigned)BCAP)
                table[(size_t)b * BCAP + off] = sm.p.stage[i];
        }
    }
}

// Pass B (one block of 512 per coarse bucket): recompute global prefix,
// LDS histogram+scan over 512 nodes, then scatter WITH per-edge softmax
// numerator p = exp(leaky(s[src]+t[dst])) and LDS-atomic denominator.
__global__ __launch_bounds__(512) void k_sp(
    const unsigned* __restrict__ table, const unsigned* __restrict__ gcur,
    const float* __restrict__ s, const float* __restrict__ t,
    uint2* __restrict__ edge_ps, unsigned* __restrict__ offsets,
    unsigned* __restrict__ counts, float* __restrict__ invden,
    int N, int NBKT, int BCAP)
{
    __shared__ unsigned ncnt[NPB], nexc[NPB], scur[NPB], sbuf[NPB];
    __shared__ float tlds[NPB], den[NPB];
    __shared__ unsigned basesh;
    const int tid = threadIdx.x;
    const int b = blockIdx.x;
    const int bc = min((int)gcur[b], BCAP);
    const size_t tbo = (size_t)b * BCAP;
    const int node = b * NPB + tid;

    {
        unsigned c = (tid < NBKT) ? min(gcur[tid], (unsigned)BCAP) : 0u;
        sbuf[tid] = c;
        __syncthreads();
        for (int off = 1; off < NPB; off <<= 1) {
            unsigned x = (tid >= off) ? sbuf[tid - off] : 0u;
            __syncthreads();
            sbuf[tid] += x;
            __syncthreads();
        }
        if (tid == 0) basesh = (b == 0) ? 0u : sbuf[b - 1];
    }
    tlds[tid] = (node < N) ? t[node] : 0.f;
    den[tid] = 0.f;
    ncnt[tid] = 0u;
    __syncthreads();
    const unsigned base = basesh;

    for (int i = tid; i < bc; i += NPB)
        atomicAdd(&ncnt[table[tbo + i] & 511u], 1u);
    __syncthreads();

    const unsigned c0 = ncnt[tid];
    sbuf[tid] = c0;
    __syncthreads();
    for (int off = 1; off < NPB; off <<= 1) {
        unsigned x = (tid >= off) ? sbuf[tid - off] : 0u;
        __syncthreads();
        sbuf[tid] += x;
        __syncthreads();
    }
    nexc[tid] = sbuf[tid] - c0;
    scur[tid] = 0u;
    __syncthreads();

    if (node < N) { offsets[node] = base + nexc[tid]; counts[node] = c0; }

    for (int i = tid; i < bc; i += NPB) {
        const unsigned v = table[tbo + i];
        const unsigned l = v & 511u;
        const unsigned sj = v >> 9;
        float e = s[sj] + tlds[l];
        e = (e >= 0.f) ? e : NEG_SLOPE * e;
        const float p = __expf(e);
        const unsigned pos = nexc[l] + atomicAdd(&scur[l], 1u);
        edge_ps[base + pos] = make_uint2(__float_as_uint(p), sj);
        atomicAdd(&den[l], p);
    }
    __syncthreads();
    if (node < N) invden[node] = 1.f / fmaxf(den[tid], 1e-16f);
}

// Pure gather-accumulate: out[node] = invden * sum p_j * z[src_j].
__global__ __launch_bounds__(256) void k_node(
    const unsigned* __restrict__ offsets, const unsigned* __restrict__ counts,
    const uint2* __restrict__ edge_ps, const float* __restrict__ invden,
    const unsigned short* __restrict__ zb, float* __restrict__ out, int N)
{
    const int tid = threadIdx.x;
    const int node = blockIdx.x * 16 + (tid >> 4);
    if (node >= N) return;
    const int wl    = tid & 63;
    const int gbase = wl & ~15;
    const int sub   = wl & 15;
    const int g2    = sub >> 3;        // edge half (0/1)
    const int l8    = sub & 7;         // dim slice

    const unsigned beg = offsets[node];
    const int cnt = (int)counts[node];
    if (cnt == 0) {
        if (sub < 8) {
            const float4 zz = make_float4(0.f, 0.f, 0.f, 0.f);
            *(float4*)&out[(size_t)node * 64 + sub * 8]     = zz;
            *(float4*)&out[(size_t)node * 64 + sub * 8 + 4] = zz;
        }
        return;
    }

    const float invd = invden[node];
    const unsigned short* __restrict__ zrow = zb + l8 * 8;
    float acc[8] = {0.f, 0.f, 0.f, 0.f, 0.f, 0.f, 0.f, 0.f};

    for (int base = 0; base < cnt; base += 16) {
        const int rem = cnt - base;
        uint2 ep = make_uint2(0u, 0u);          // p=0, sj=0 for inactive slots
        if (sub < rem) ep = edge_ps[beg + base + sub];
        const float p = __uint_as_float(ep.x);
        const int  sj = (int)ep.y;

        uint4 vv[8];
#pragma unroll
        for (int k = 0; k < 8; ++k) {
            const int sjj = __shfl(sj, gbase + g2 * 8 + k);
            vv[k] = *(const uint4*)&zrow[(size_t)sjj * 64];
        }
#pragma unroll
        for (int k = 0; k < 8; ++k) {
            const float pj = __shfl(p, gbase + g2 * 8 + k);
            const uint4 v = vv[k];
#define UNPK(u, d0) \
            acc[d0]     = fmaf(pj, __uint_as_float((u) << 16),          acc[d0]); \
            acc[d0 + 1] = fmaf(pj, __uint_as_float((u) & 0xFFFF0000u), acc[d0 + 1]);
            UNPK(v.x, 0) UNPK(v.y, 2) UNPK(v.z, 4) UNPK(v.w, 6)
#undef UNPK
        }
    }

#pragma unroll
    for (int c = 0; c < 8; ++c)
        acc[c] += __shfl_xor(acc[c], 8);

    if (sub < 8) {
        float4 o0 = make_float4(acc[0] * invd, acc[1] * invd, acc[2] * invd, acc[3] * invd);
        float4 o1 = make_float4(acc[4] * invd, acc[5] * invd, acc[6] * invd, acc[7] * invd);
        *(float4*)&out[(size_t)node * 64 + sub * 8]     = o0;
        *(float4*)&out[(size_t)node * 64 + sub * 8 + 4] = o1;
    }
}

extern "C" void kernel_launch(void* const* d_in, const int* in_sizes, int n_in,
                              void* d_out, int out_size, void* d_ws, size_t ws_size,
                              hipStream_t stream) {
    const float* h   = (const float*)d_in[0];
    const int*   src = (const int*)d_in[1];
    const int*   dst = (const int*)d_in[2];
    const float* W1  = (const float*)d_in[3];
    const float* Wa  = (const float*)d_in[4];
    float* out = (float*)d_out;

    const int N = in_sizes[0] / 128;
    const int E = in_sizes[1];
    const int NBKT = (N + NPB - 1) / NPB;            // <=256
    const int meanb = (E + NBKT - 1) / NBKT;
    int slack = 24 * (int)sqrtf((float)meanb) + 64;  // mean + 24 sigma
    const int BCAP = meanb + slack;

    const int G1 = (N + 255) / 256;                  // gemm blocks (256 rows each)
    const int G2 = (E + CHUNK - 1) / CHUNK;          // partition blocks

    // ws: zb(N*64 bf16) | s(N) | t(N) | gcur(NBKT) | offsets(N) | counts(N) |
    //     invden(N) | edge_ps(E u64) | table(NBKT*BCAP)
    unsigned short* zb = (unsigned short*)d_ws;
    float*    s        = (float*)(zb + (size_t)N * 64);
    float*    t        = s + N;
    unsigned* gcur     = (unsigned*)(t + N);
    unsigned* offsets  = gcur + NBKT;
    unsigned* counts   = offsets + N;
    float*    invden   = (float*)(counts + N);
    uint2*    edge_ps  = (uint2*)(invden + N);
    unsigned* table    = (unsigned*)(edge_ps + E);

    hipMemsetAsync(gcur, 0, (size_t)NBKT * sizeof(unsigned), stream);

    k_gp<<<G1 + G2, 256, 0, stream>>>(h, W1, Wa, zb, s, t, N, G1,
                                      src, dst, gcur, table, E, NBKT, BCAP);
    k_sp<<<NBKT, 512, 0, stream>>>(table, gcur, s, t, edge_ps, offsets, counts,
                                   invden, N, NBKT, BCAP);
    k_node<<<(N + 15) / 16, 256, 0, stream>>>(offsets, counts, edge_ps, invden, zb, out, N);
}